// Round 3
// baseline (424.458 us; speedup 1.0000x reference)
//
#include <hip/hip_runtime.h>
#include <stdint.h>

// R9: base = R8 except attn processes TWO q-tiles per block (QBLK=128) against
// each staged K/V tile. Rationale (counters: MFMA 8%, VALU 33%, HBM 4%,
// bank-conflict flat): latency-bound serial chain per iteration with too
// little independent work. Doubling q-tiles per wave doubles ILP per
// barrier, halves staging and barrier cost per unit compute, halves
// K/V re-fetch. Dataflow per tile is R8's verified swapped-QK^T structure.

typedef unsigned short u16;
typedef short bf16x8 __attribute__((ext_vector_type(8)));
typedef float f32x4 __attribute__((ext_vector_type(4)));

#define D_MODEL 2048
#define QKV_DIM 3072
#define NUM_HEADS 32
#define HEAD_DIM 64
#define SEQ 2048
#define MTOT 4096

static __device__ __forceinline__ u16 f2bf(float f){
  uint32_t u = __builtin_bit_cast(uint32_t, f);
  u += 0x7FFFu + ((u >> 16) & 1u);
  return (u16)(u >> 16);
}

static __device__ __forceinline__ void gload16(const u16* g, u16* l){
  __builtin_amdgcn_global_load_lds(
      (__attribute__((address_space(1))) uint32_t*)(uintptr_t)g,
      (__attribute__((address_space(3))) uint32_t*)l,
      16, 0, 0);
}

__global__ __launch_bounds__(256)
void cvt_bf16(const float* __restrict__ in, u16* __restrict__ out, int n){
  const int i = (blockIdx.x * 256 + threadIdx.x) * 8;
  if (i >= n) return;
  float4 a = *(const float4*)(in + i);
  float4 b = *(const float4*)(in + i + 4);
  union { u16 h[8]; uint4 v; } t;
  t.h[0]=f2bf(a.x); t.h[1]=f2bf(a.y); t.h[2]=f2bf(a.z); t.h[3]=f2bf(a.w);
  t.h[4]=f2bf(b.x); t.h[5]=f2bf(b.y); t.h[6]=f2bf(b.z); t.h[7]=f2bf(b.w);
  *(uint4*)(out + i) = t.v;
}

// C[M,N] = A[M,K] @ B[N,K]^T (m97 structure, unchanged).
template <bool F32OUT>
__global__ __launch_bounds__(256)
void gemm_bt(const u16* __restrict__ A, const u16* __restrict__ B,
             void* __restrict__ Cv, int M, int N, int K){
  constexpr int BK = 32;
  __shared__ __attribute__((aligned(16))) u16 As[128*BK];
  __shared__ __attribute__((aligned(16))) u16 Bs[128*BK];
  const int tid  = threadIdx.x;
  const int wave = tid >> 6, lane = tid & 63;
  const int quad = lane >> 4, l16 = lane & 15;
  const int wrow = wave >> 1, wcol = wave & 1;
  const int m0 = blockIdx.y * 128, n0 = blockIdx.x * 128;
  const int srow = lane >> 2, scol = (lane & 3) * 8;

  const f32x4 zero = {0.f, 0.f, 0.f, 0.f};
  f32x4 acc[4][4];
#pragma unroll
  for (int i = 0; i < 4; i++)
#pragma unroll
    for (int j = 0; j < 4; j++) acc[i][j] = zero;

  for (int k0 = 0; k0 < K; k0 += BK){
#pragma unroll
    for (int t = 0; t < 2; t++){
      const int chunk = wave + t*4;
      gload16(A + (size_t)(m0 + chunk*16 + srow)*K + k0 + scol, As + chunk*16*BK);
      gload16(B + (size_t)(n0 + chunk*16 + srow)*K + k0 + scol, Bs + chunk*16*BK);
    }
    __syncthreads();
    bf16x8 af[4], bfr[4];
#pragma unroll
    for (int mi = 0; mi < 4; mi++)
      af[mi] = *(const bf16x8*)(As + (wrow*64 + mi*16 + l16)*BK + quad*8);
#pragma unroll
    for (int ni = 0; ni < 4; ni++)
      bfr[ni] = *(const bf16x8*)(Bs + (wcol*64 + ni*16 + l16)*BK + quad*8);
#pragma unroll
    for (int mi = 0; mi < 4; mi++)
#pragma unroll
      for (int ni = 0; ni < 4; ni++)
        acc[mi][ni] = __builtin_amdgcn_mfma_f32_16x16x32_bf16(af[mi], bfr[ni], acc[mi][ni], 0, 0, 0);
    __syncthreads();
  }
#pragma unroll
  for (int mi = 0; mi < 4; mi++)
#pragma unroll
    for (int ni = 0; ni < 4; ni++){
      const int col = n0 + wcol*64 + ni*16 + l16;
#pragma unroll
      for (int r = 0; r < 4; r++){
        const int row = m0 + wrow*64 + mi*16 + quad*4 + r;
        if constexpr (F32OUT)
          ((float*)Cv)[(size_t)row*N + col] = acc[mi][ni][r];
        else
          ((u16*)Cv)[(size_t)row*N + col] = f2bf(acc[mi][ni][r]);
      }
    }
}

// V^T pre-transpose: VT[(b*8+hk)*64 + d][s] = QKV[b*2048+s][2560 + hk*64 + d]
__global__ __launch_bounds__(256)
void vtrans(const u16* __restrict__ QKV, u16* __restrict__ VT){
  __shared__ u16 Ls[64*72];
  const int tid = threadIdx.x;
  const int st = blockIdx.x, hk = blockIdx.y, b = blockIdx.z;
  const size_t rb = (size_t)b * SEQ;
#pragma unroll
  for (int t = 0; t < 2; t++){
    const int task = t*256 + tid;
    const int r = task >> 3, c = task & 7;
    *(uint4*)(Ls + r*72 + c*8) =
        *(const uint4*)(QKV + (rb + st*64 + r)*QKV_DIM + 2560 + hk*HEAD_DIM + c*8);
  }
  __syncthreads();
  u16* vt_g = VT + ((size_t)(b*8 + hk) * 64) * SEQ;
#pragma unroll
  for (int t = 0; t < 2; t++){
    const int task = t*256 + tid;
    const int d = task >> 3, sc = task & 7;
    union { u16 h[8]; uint4 v; } tmp;
#pragma unroll
    for (int e = 0; e < 8; e++) tmp.h[e] = Ls[(sc*8 + e)*72 + d];
    *(uint4*)(vt_g + (size_t)d*SEQ + st*64 + sc*8) = tmp.v;
  }
}

// --- attn helpers: one q-tile's QK + online-softmax + P spill, and PV ---
static __device__ __forceinline__ void qksm(
    const u16* __restrict__ Ksb, u16* __restrict__ Pw,
    const bf16x8* qf, f32x4* oacc, float& m_i, float& l_i,
    int quad, int l16, bool diag, int qrow){
  constexpr int KP = 72;
  const f32x4 zero = {0.f, 0.f, 0.f, 0.f};
  f32x4 st[4];
#pragma unroll
  for (int ni = 0; ni < 4; ni++){
    f32x4 s = zero;
#pragma unroll
    for (int ss = 0; ss < 2; ss++){
      bf16x8 kf = *(const bf16x8*)(Ksb + (ni*16 + l16)*KP + ss*32 + quad*8);
      s = __builtin_amdgcn_mfma_f32_16x16x32_bf16(kf, qf[ss], s, 0, 0, 0);
    }
#pragma unroll
    for (int r = 0; r < 4; r++) st[ni][r] = s[r] * 0.125f;
  }
  if (diag){
#pragma unroll
    for (int ni = 0; ni < 4; ni++)
#pragma unroll
      for (int r = 0; r < 4; r++)
        if (ni*16 + quad*4 + r > qrow) st[ni][r] = -INFINITY;
  }
  float mx = fmaxf(fmaxf(fmaxf(st[0][0], st[0][1]), fmaxf(st[0][2], st[0][3])),
                   fmaxf(fmaxf(st[1][0], st[1][1]), fmaxf(st[1][2], st[1][3])));
  mx = fmaxf(mx, fmaxf(fmaxf(fmaxf(st[2][0], st[2][1]), fmaxf(st[2][2], st[2][3])),
                       fmaxf(fmaxf(st[3][0], st[3][1]), fmaxf(st[3][2], st[3][3]))));
  mx = fmaxf(mx, __shfl_xor(mx, 16));
  mx = fmaxf(mx, __shfl_xor(mx, 32));
  const float mn = fmaxf(m_i, mx);
  const float alpha = __expf(m_i - mn);
  float ps = 0.f;
#pragma unroll
  for (int ni = 0; ni < 4; ni++)
#pragma unroll
    for (int r = 0; r < 4; r++){
      const float p = __expf(st[ni][r] - mn);
      st[ni][r] = p;
      ps += p;
    }
  ps += __shfl_xor(ps, 16);
  ps += __shfl_xor(ps, 32);
  l_i = l_i*alpha + ps;
  m_i = mn;
  float ar[4];
#pragma unroll
  for (int r = 0; r < 4; r++) ar[r] = __shfl(alpha, quad*4 + r);
#pragma unroll
  for (int ci = 0; ci < 4; ci++)
#pragma unroll
    for (int r = 0; r < 4; r++) oacc[ci][r] *= ar[r];
#pragma unroll
  for (int ni = 0; ni < 4; ni++){
    union { u16 h[4]; uint2 v; } pk;
    pk.h[0] = f2bf(st[ni][0]); pk.h[1] = f2bf(st[ni][1]);
    pk.h[2] = f2bf(st[ni][2]); pk.h[3] = f2bf(st[ni][3]);
    *(uint2*)(Pw + l16*KP + ni*16 + quad*4) = pk.v;
  }
}

static __device__ __forceinline__ void pvacc(
    const u16* __restrict__ Pw, const u16* __restrict__ Vts,
    f32x4* oacc, int quad, int l16){
  constexpr int KP = 72;
#pragma unroll
  for (int ss = 0; ss < 2; ss++){
    bf16x8 pf = *(const bf16x8*)(Pw + l16*KP + ss*32 + quad*8);
#pragma unroll
    for (int ci = 0; ci < 4; ci++){
      bf16x8 vf = *(const bf16x8*)(Vts + (ci*16 + l16)*KP + ss*32 + quad*8);
      oacc[ci] = __builtin_amdgcn_mfma_f32_16x16x32_bf16(pf, vf, oacc[ci], 0, 0, 0);
    }
  }
}

// attn: QBLK=128 (two q-tiles per block), swapped QK^T, reg-prefetch, LPT.
__global__ __launch_bounds__(256)
void attn(const u16* __restrict__ Q, const u16* __restrict__ Kp,
          const u16* __restrict__ VT, u16* __restrict__ O, int qs, int ks){
  constexpr int KP = 72;
  __shared__ __attribute__((aligned(16))) u16 Ks[64*KP];
  __shared__ __attribute__((aligned(16))) u16 Vt[64*KP];
  __shared__ __attribute__((aligned(16))) u16 Ps[8*16*KP];
  const int tid = threadIdx.x;
  const int wave = tid >> 6, lane = tid & 63, quad = lane >> 4, l16 = lane & 15;
  const int tpair = (SEQ/128 - 1) - blockIdx.x;  // LPT: longest first
  const int qA = 2*tpair, qB = 2*tpair + 1;
  const int h = blockIdx.y, b = blockIdx.z;
  const int hk = h >> 2;
  const size_t rb = (size_t)b * SEQ;
  const u16* vt_g = VT + ((size_t)(b*8 + hk) * 64) * SEQ;

  const int sr = tid >> 2, sc = tid & 3;
  const int qrow = wave*16 + l16;   // this lane's q-row within its tile

  bf16x8 qfA[2], qfB[2];
  {
    const u16* qpA = Q + (rb + qA*64 + wave*16 + l16)*qs + h*HEAD_DIM;
    qfA[0] = *(const bf16x8*)(qpA + quad*8);
    qfA[1] = *(const bf16x8*)(qpA + 32 + quad*8);
    const u16* qpB = Q + (rb + qB*64 + wave*16 + l16)*qs + h*HEAD_DIM;
    qfB[0] = *(const bf16x8*)(qpB + quad*8);
    qfB[1] = *(const bf16x8*)(qpB + 32 + quad*8);
  }
  const f32x4 zero = {0.f, 0.f, 0.f, 0.f};
  f32x4 oA[4], oB[4];
#pragma unroll
  for (int i = 0; i < 4; i++){ oA[i] = zero; oB[i] = zero; }
  float mA = -INFINITY, lA = 0.f, mB = -INFINITY, lB = 0.f;
  u16* PwA = Ps + wave*16*KP;
  u16* PwB = Ps + (4 + wave)*16*KP;

  // prologue: prefetch tile j=0 into registers
  uint4 kreg0, kreg1, vreg0, vreg1;
  {
    const u16* kg = Kp + (rb + sr)*ks + hk*HEAD_DIM;
    kreg0 = *(const uint4*)(kg + sc*8);
    kreg1 = *(const uint4*)(kg + (sc+4)*8);
    const u16* vg = vt_g + (size_t)sr*SEQ;
    vreg0 = *(const uint4*)(vg + sc*8);
    vreg1 = *(const uint4*)(vg + (sc+4)*8);
  }

  for (int j = 0; j <= qB; ++j){
    *(uint4*)(Ks + sr*KP + sc*8)     = kreg0;
    *(uint4*)(Ks + sr*KP + (sc+4)*8) = kreg1;
    *(uint4*)(Vt + sr*KP + sc*8)     = vreg0;
    *(uint4*)(Vt + sr*KP + (sc+4)*8) = vreg1;
    __syncthreads();
    if (j < qB){
      const u16* kg = Kp + (rb + (j+1)*64 + sr)*ks + hk*HEAD_DIM;
      kreg0 = *(const uint4*)(kg + sc*8);
      kreg1 = *(const uint4*)(kg + (sc+4)*8);
      const u16* vg = vt_g + (size_t)sr*SEQ + (j+1)*64;
      vreg0 = *(const uint4*)(vg + sc*8);
      vreg1 = *(const uint4*)(vg + (sc+4)*8);
    }

    const bool doA = (j <= qA);
    if (doA) qksm(Ks, PwA, qfA, oA, mA, lA, quad, l16, j == qA, qrow);
    qksm(Ks, PwB, qfB, oB, mB, lB, quad, l16, j == qB, qrow);

    __asm__ volatile("s_waitcnt lgkmcnt(0)" ::: "memory");
    if (doA) pvacc(PwA, Vt, oA, quad, l16);
    pvacc(PwB, Vt, oB, quad, l16);
    __syncthreads();
  }

  float lfA[4], lfB[4];
#pragma unroll
  for (int r = 0; r < 4; r++){
    lfA[r] = __shfl(lA, quad*4 + r);
    lfB[r] = __shfl(lB, quad*4 + r);
  }
#pragma unroll
  for (int ci = 0; ci < 4; ci++)
#pragma unroll
    for (int r = 0; r < 4; r++){
      const size_t rowA = rb + qA*64 + wave*16 + quad*4 + r;
      O[rowA*D_MODEL + h*HEAD_DIM + ci*16 + l16] = f2bf(oA[ci][r] / lfA[r]);
      const size_t rowB = rb + qB*64 + wave*16 + quad*4 + r;
      O[rowB*D_MODEL + h*HEAD_DIM + ci*16 + l16] = f2bf(oB[ci][r] / lfB[r]);
    }
}

extern "C" void kernel_launch(void* const* d_in, const int* in_sizes, int n_in,
                              void* d_out, int out_size, void* d_ws, size_t ws_size,
                              hipStream_t stream){
  const float* x  = (const float*)d_in[0];
  const float* Wq = (const float*)d_in[1];
  const float* Wk = (const float*)d_in[2];
  const float* Wv = (const float*)d_in[3];
  const float* Wo = (const float*)d_in[4];
  float* out = (float*)d_out;

  u16* xb   = (u16*)d_ws;                    // x / later attn-out  [4096,2048]
  u16* Wb   = xb + (size_t)MTOT*D_MODEL;     // fused weights [3072,2048]
  u16* VTb  = Wb + (size_t)QKV_DIM*D_MODEL;  // V^T [16*64, 2048] (own slot)
  u16* QKVb = (u16*)d_out;                   // QKV scratch [4096,3072] bf16

  const int nx  = MTOT*D_MODEL;
  const int nwq = D_MODEL*D_MODEL;
  const int nwk = 512*D_MODEL;

  cvt_bf16<<<nx/2048, 256, 0, stream>>>(x, xb, nx);
  cvt_bf16<<<nwq/2048, 256, 0, stream>>>(Wq, Wb, nwq);
  cvt_bf16<<<nwk/2048, 256, 0, stream>>>(Wk, Wb + (size_t)D_MODEL*D_MODEL, nwk);
  cvt_bf16<<<nwk/2048, 256, 0, stream>>>(Wv, Wb + (size_t)2560*D_MODEL, nwk);
  gemm_bt<false><<<dim3(QKV_DIM/128, MTOT/128), 256, 0, stream>>>(xb, Wb, QKVb, MTOT, QKV_DIM, D_MODEL);
  vtrans<<<dim3(SEQ/64, 8, 2), 256, 0, stream>>>(QKVb, VTb);
  attn<<<dim3(SEQ/128, NUM_HEADS, 2), 256, 0, stream>>>(
      QKVb, QKVb + D_MODEL, VTb, xb, QKV_DIM, QKV_DIM);
  cvt_bf16<<<nwq/2048, 256, 0, stream>>>(Wo, Wb, nwq);
  gemm_bt<true><<<dim3(D_MODEL/128, MTOT/128), 256, 0, stream>>>(xb, Wb, (void*)out, MTOT, D_MODEL, D_MODEL);
}

// Round 4
// 393.310 us; speedup vs baseline: 1.0792x; 1.0792x over previous
//
#include <hip/hip_runtime.h>
#include <stdint.h>

// R10: base = R8 (single q-tile/block, 2048 blocks — R9's pairing regressed
// on occupancy). ONE structural change: the P matrix never touches LDS.
// In the swapped-QK layout each lane owns P[qrow=l16][keys ni*16+quad*4+r];
// by permuting the PV contraction's k-order (baked into vtrans's V column
// order), those 16 values ARE the lane's PV A-fragment. Deletes the
// per-iteration ds_write->lgkmcnt(0)->ds_read round-trip and the Ps buffer
// (LDS 27648->18432 B => 8 blocks/CU, was 5).

typedef unsigned short u16;
typedef short bf16x8 __attribute__((ext_vector_type(8)));
typedef float f32x4 __attribute__((ext_vector_type(4)));

#define D_MODEL 2048
#define QKV_DIM 3072
#define NUM_HEADS 32
#define HEAD_DIM 64
#define SEQ 2048
#define MTOT 4096

static __device__ __forceinline__ u16 f2bf(float f){
  uint32_t u = __builtin_bit_cast(uint32_t, f);
  u += 0x7FFFu + ((u >> 16) & 1u);
  return (u16)(u >> 16);
}

static __device__ __forceinline__ void gload16(const u16* g, u16* l){
  __builtin_amdgcn_global_load_lds(
      (__attribute__((address_space(1))) uint32_t*)(uintptr_t)g,
      (__attribute__((address_space(3))) uint32_t*)l,
      16, 0, 0);
}

__global__ __launch_bounds__(256)
void cvt_bf16(const float* __restrict__ in, u16* __restrict__ out, int n){
  const int i = (blockIdx.x * 256 + threadIdx.x) * 8;
  if (i >= n) return;
  float4 a = *(const float4*)(in + i);
  float4 b = *(const float4*)(in + i + 4);
  union { u16 h[8]; uint4 v; } t;
  t.h[0]=f2bf(a.x); t.h[1]=f2bf(a.y); t.h[2]=f2bf(a.z); t.h[3]=f2bf(a.w);
  t.h[4]=f2bf(b.x); t.h[5]=f2bf(b.y); t.h[6]=f2bf(b.z); t.h[7]=f2bf(b.w);
  *(uint4*)(out + i) = t.v;
}

// C[M,N] = A[M,K] @ B[N,K]^T (m97 structure, unchanged).
template <bool F32OUT>
__global__ __launch_bounds__(256)
void gemm_bt(const u16* __restrict__ A, const u16* __restrict__ B,
             void* __restrict__ Cv, int M, int N, int K){
  constexpr int BK = 32;
  __shared__ __attribute__((aligned(16))) u16 As[128*BK];
  __shared__ __attribute__((aligned(16))) u16 Bs[128*BK];
  const int tid  = threadIdx.x;
  const int wave = tid >> 6, lane = tid & 63;
  const int quad = lane >> 4, l16 = lane & 15;
  const int wrow = wave >> 1, wcol = wave & 1;
  const int m0 = blockIdx.y * 128, n0 = blockIdx.x * 128;
  const int srow = lane >> 2, scol = (lane & 3) * 8;

  const f32x4 zero = {0.f, 0.f, 0.f, 0.f};
  f32x4 acc[4][4];
#pragma unroll
  for (int i = 0; i < 4; i++)
#pragma unroll
    for (int j = 0; j < 4; j++) acc[i][j] = zero;

  for (int k0 = 0; k0 < K; k0 += BK){
#pragma unroll
    for (int t = 0; t < 2; t++){
      const int chunk = wave + t*4;
      gload16(A + (size_t)(m0 + chunk*16 + srow)*K + k0 + scol, As + chunk*16*BK);
      gload16(B + (size_t)(n0 + chunk*16 + srow)*K + k0 + scol, Bs + chunk*16*BK);
    }
    __syncthreads();
    bf16x8 af[4], bfr[4];
#pragma unroll
    for (int mi = 0; mi < 4; mi++)
      af[mi] = *(const bf16x8*)(As + (wrow*64 + mi*16 + l16)*BK + quad*8);
#pragma unroll
    for (int ni = 0; ni < 4; ni++)
      bfr[ni] = *(const bf16x8*)(Bs + (wcol*64 + ni*16 + l16)*BK + quad*8);
#pragma unroll
    for (int mi = 0; mi < 4; mi++)
#pragma unroll
      for (int ni = 0; ni < 4; ni++)
        acc[mi][ni] = __builtin_amdgcn_mfma_f32_16x16x32_bf16(af[mi], bfr[ni], acc[mi][ni], 0, 0, 0);
    __syncthreads();
  }
#pragma unroll
  for (int mi = 0; mi < 4; mi++)
#pragma unroll
    for (int ni = 0; ni < 4; ni++){
      const int col = n0 + wcol*64 + ni*16 + l16;
#pragma unroll
      for (int r = 0; r < 4; r++){
        const int row = m0 + wrow*64 + mi*16 + quad*4 + r;
        if constexpr (F32OUT)
          ((float*)Cv)[(size_t)row*N + col] = acc[mi][ni][r];
        else
          ((u16*)Cv)[(size_t)row*N + col] = f2bf(acc[mi][ni][r]);
      }
    }
}

// V^T pre-transpose with PV k-order permutation baked into the column order:
// within each 64-key tile, column (32*ss + 8*q + 4*ni' + r) holds key
// ((2*ss+ni')*16 + q*4 + r). attn then reads V fragments at natural offsets
// while each lane's own P values form its A-fragment.
__global__ __launch_bounds__(256)
void vtrans(const u16* __restrict__ QKV, u16* __restrict__ VT){
  __shared__ u16 Ls[64*72];
  const int tid = threadIdx.x;
  const int st = blockIdx.x, hk = blockIdx.y, b = blockIdx.z;
  const size_t rb = (size_t)b * SEQ;
#pragma unroll
  for (int t = 0; t < 2; t++){
    const int task = t*256 + tid;
    const int r = task >> 3, c = task & 7;
    *(uint4*)(Ls + r*72 + c*8) =
        *(const uint4*)(QKV + (rb + st*64 + r)*QKV_DIM + 2560 + hk*HEAD_DIM + c*8);
  }
  __syncthreads();
  u16* vt_g = VT + ((size_t)(b*8 + hk) * 64) * SEQ;
#pragma unroll
  for (int t = 0; t < 2; t++){
    const int task = t*256 + tid;
    const int d = task >> 3, sc = task & 7;
    union { u16 h[8]; uint4 v; } tmp;
#pragma unroll
    for (int e = 0; e < 8; e++){
      const int key = ((2*(sc>>2) + (e>>2))<<4) + ((sc&3)<<2) + (e&3);
      tmp.h[e] = Ls[key*72 + d];
    }
    *(uint4*)(vt_g + (size_t)d*SEQ + st*64 + sc*8) = tmp.v;
  }
}

// attn: swapped QK^T, in-register P (no LDS round-trip), reg-prefetch, LPT.
__global__ __launch_bounds__(256)
void attn(const u16* __restrict__ Q, const u16* __restrict__ Kp,
          const u16* __restrict__ VT, u16* __restrict__ O, int qs, int ks){
  constexpr int KP = 72;
  __shared__ __attribute__((aligned(16))) u16 Ks[64*KP];
  __shared__ __attribute__((aligned(16))) u16 Vt[64*KP];
  const int tid = threadIdx.x;
  const int wave = tid >> 6, lane = tid & 63, quad = lane >> 4, l16 = lane & 15;
  const int qt = (SEQ/64 - 1) - blockIdx.x;   // LPT: longest blocks first
  const int h = blockIdx.y, b = blockIdx.z;
  const int hk = h >> 2;
  const size_t rb = (size_t)b * SEQ;
  const u16* vt_g = VT + ((size_t)(b*8 + hk) * 64) * SEQ;

  const int sr = tid >> 2, sc = tid & 3;
  const int qrow = wave*16 + l16;   // this lane's q-row (swapped layout)

  bf16x8 qf[2];
  {
    const u16* qp = Q + (rb + qt*64 + wave*16 + l16)*qs + h*HEAD_DIM;
    qf[0] = *(const bf16x8*)(qp + quad*8);
    qf[1] = *(const bf16x8*)(qp + 32 + quad*8);
  }
  const f32x4 zero = {0.f, 0.f, 0.f, 0.f};
  f32x4 oacc[4];
#pragma unroll
  for (int i = 0; i < 4; i++) oacc[i] = zero;
  float m_i = -INFINITY;
  float l_i = 0.f;

  // prologue: prefetch tile j=0 into registers
  uint4 kreg0, kreg1, vreg0, vreg1;
  {
    const u16* kg = Kp + (rb + sr)*ks + hk*HEAD_DIM;
    kreg0 = *(const uint4*)(kg + sc*8);
    kreg1 = *(const uint4*)(kg + (sc+4)*8);
    const u16* vg = vt_g + (size_t)sr*SEQ;
    vreg0 = *(const uint4*)(vg + sc*8);
    vreg1 = *(const uint4*)(vg + (sc+4)*8);
  }

  for (int j = 0; j <= qt; ++j){
    *(uint4*)(Ks + sr*KP + sc*8)     = kreg0;
    *(uint4*)(Ks + sr*KP + (sc+4)*8) = kreg1;
    *(uint4*)(Vt + sr*KP + sc*8)     = vreg0;
    *(uint4*)(Vt + sr*KP + (sc+4)*8) = vreg1;
    __syncthreads();
    if (j < qt){
      const u16* kg = Kp + (rb + (j+1)*64 + sr)*ks + hk*HEAD_DIM;
      kreg0 = *(const uint4*)(kg + sc*8);
      kreg1 = *(const uint4*)(kg + (sc+4)*8);
      const u16* vg = vt_g + (size_t)sr*SEQ + (j+1)*64;
      vreg0 = *(const uint4*)(vg + sc*8);
      vreg1 = *(const uint4*)(vg + (sc+4)*8);
    }

    // QK^T swapped: st[ni][r] = S[key = j*64 + ni*16 + quad*4 + r][qrow l16]
    f32x4 st[4];
#pragma unroll
    for (int ni = 0; ni < 4; ni++){
      f32x4 s = zero;
#pragma unroll
      for (int ss = 0; ss < 2; ss++){
        bf16x8 kf = *(const bf16x8*)(Ks + (ni*16 + l16)*KP + ss*32 + quad*8);
        s = __builtin_amdgcn_mfma_f32_16x16x32_bf16(kf, qf[ss], s, 0, 0, 0);
      }
#pragma unroll
      for (int r = 0; r < 4; r++) st[ni][r] = s[r] * 0.125f;
    }
    if (j == qt){
#pragma unroll
      for (int ni = 0; ni < 4; ni++)
#pragma unroll
        for (int r = 0; r < 4; r++)
          if (ni*16 + quad*4 + r > qrow) st[ni][r] = -INFINITY;
    }

    // per-lane softmax over this row's 16 values + 2 shfl quad-combine
    float mx = fmaxf(fmaxf(fmaxf(st[0][0], st[0][1]), fmaxf(st[0][2], st[0][3])),
                     fmaxf(fmaxf(st[1][0], st[1][1]), fmaxf(st[1][2], st[1][3])));
    mx = fmaxf(mx, fmaxf(fmaxf(fmaxf(st[2][0], st[2][1]), fmaxf(st[2][2], st[2][3])),
                         fmaxf(fmaxf(st[3][0], st[3][1]), fmaxf(st[3][2], st[3][3]))));
    mx = fmaxf(mx, __shfl_xor(mx, 16));
    mx = fmaxf(mx, __shfl_xor(mx, 32));
    const float mn = fmaxf(m_i, mx);
    const float alpha = __expf(m_i - mn);
    float ps = 0.f;
#pragma unroll
    for (int ni = 0; ni < 4; ni++)
#pragma unroll
      for (int r = 0; r < 4; r++){
        const float p = __expf(st[ni][r] - mn);
        st[ni][r] = p;
        ps += p;
      }
    ps += __shfl_xor(ps, 16);
    ps += __shfl_xor(ps, 32);
    l_i = l_i*alpha + ps;
    m_i = mn;

    // broadcast alpha from lane-space (row=l16) to oacc row-space (row=quad*4+r)
    float ar[4];
#pragma unroll
    for (int r = 0; r < 4; r++) ar[r] = __shfl(alpha, quad*4 + r);
#pragma unroll
    for (int ci = 0; ci < 4; ci++)
#pragma unroll
      for (int r = 0; r < 4; r++) oacc[ci][r] *= ar[r];

    // P stays in registers: lane's 16 values ARE its PV A-fragment under the
    // k-permutation baked into vtrans. pf[ss][4*ni'+r] = P[key (2ss+ni')*16+quad*4+r]
    bf16x8 pfr[2];
#pragma unroll
    for (int ss = 0; ss < 2; ss++)
#pragma unroll
      for (int n2 = 0; n2 < 2; n2++)
#pragma unroll
        for (int r = 0; r < 4; r++)
          pfr[ss][n2*4 + r] = (short)f2bf(st[2*ss + n2][r]);

#pragma unroll
    for (int ss = 0; ss < 2; ss++)
#pragma unroll
      for (int ci = 0; ci < 4; ci++){
        bf16x8 vf = *(const bf16x8*)(Vt + (ci*16 + l16)*KP + ss*32 + quad*8);
        oacc[ci] = __builtin_amdgcn_mfma_f32_16x16x32_bf16(pfr[ss], vf, oacc[ci], 0, 0, 0);
      }
    __syncthreads();
  }

  // final: l_i lives in lane-space (row=l16); broadcast to row-space
  float lf[4];
#pragma unroll
  for (int r = 0; r < 4; r++) lf[r] = __shfl(l_i, quad*4 + r);
#pragma unroll
  for (int ci = 0; ci < 4; ci++)
#pragma unroll
    for (int r = 0; r < 4; r++){
      const size_t row = rb + qt*64 + wave*16 + quad*4 + r;
      O[row*D_MODEL + h*HEAD_DIM + ci*16 + l16] = f2bf(oacc[ci][r] / lf[r]);
    }
}

extern "C" void kernel_launch(void* const* d_in, const int* in_sizes, int n_in,
                              void* d_out, int out_size, void* d_ws, size_t ws_size,
                              hipStream_t stream){
  const float* x  = (const float*)d_in[0];
  const float* Wq = (const float*)d_in[1];
  const float* Wk = (const float*)d_in[2];
  const float* Wv = (const float*)d_in[3];
  const float* Wo = (const float*)d_in[4];
  float* out = (float*)d_out;

  u16* xb   = (u16*)d_ws;                    // x / later attn-out  [4096,2048]
  u16* Wb   = xb + (size_t)MTOT*D_MODEL;     // fused weights [3072,2048]
  u16* VTb  = Wb + (size_t)QKV_DIM*D_MODEL;  // V^T [16*64, 2048] (own slot)
  u16* QKVb = (u16*)d_out;                   // QKV scratch [4096,3072] bf16

  const int nx  = MTOT*D_MODEL;
  const int nwq = D_MODEL*D_MODEL;
  const int nwk = 512*D_MODEL;

  cvt_bf16<<<nx/2048, 256, 0, stream>>>(x, xb, nx);
  cvt_bf16<<<nwq/2048, 256, 0, stream>>>(Wq, Wb, nwq);
  cvt_bf16<<<nwk/2048, 256, 0, stream>>>(Wk, Wb + (size_t)D_MODEL*D_MODEL, nwk);
  cvt_bf16<<<nwk/2048, 256, 0, stream>>>(Wv, Wb + (size_t)2560*D_MODEL, nwk);
  gemm_bt<false><<<dim3(QKV_DIM/128, MTOT/128), 256, 0, stream>>>(xb, Wb, QKVb, MTOT, QKV_DIM, D_MODEL);
  vtrans<<<dim3(SEQ/64, 8, 2), 256, 0, stream>>>(QKVb, VTb);
  attn<<<dim3(SEQ/64, NUM_HEADS, 2), 256, 0, stream>>>(
      QKVb, QKVb + D_MODEL, VTb, xb, QKV_DIM, QKV_DIM);
  cvt_bf16<<<nwq/2048, 256, 0, stream>>>(Wo, Wb, nwq);
  gemm_bt<true><<<dim3(D_MODEL/128, MTOT/128), 256, 0, stream>>>(xb, Wb, (void*)out, MTOT, D_MODEL, D_MODEL);
}

// Round 5
// 380.597 us; speedup vs baseline: 1.1152x; 1.0334x over previous
//
#include <hip/hip_runtime.h>
#include <stdint.h>

// R11: base = R10 verbatim except attn softmax/P-conversion micro-structure:
//  1. P -> bf16 via v_cvt_pk_bf16_f32 (8 packed converts instead of 64 VALU
//     ops of manual RNE bit-twiddling) -- T12 primitive.
//  2. log2-domain softmax: scale = 0.125*log2e folded into the one existing
//     mul; exponentials are raw v_exp_f32 (=2^x), dropping __expf's hidden
//     *log2e mul. Mathematically identical softmax.
//  3. defer-max (T13, THR=10 log2-units): skip alpha/shfl-broadcast/oacc
//     rescale when the running max doesn't grow; p bounded by 2^10.
// No LDS/grid/occupancy changes (R9 lesson: don't trade occupancy for ILP).

typedef unsigned short u16;
typedef short bf16x8 __attribute__((ext_vector_type(8)));
typedef float f32x4 __attribute__((ext_vector_type(4)));

#define D_MODEL 2048
#define QKV_DIM 3072
#define NUM_HEADS 32
#define HEAD_DIM 64
#define SEQ 2048
#define MTOT 4096

static __device__ __forceinline__ u16 f2bf(float f){
  uint32_t u = __builtin_bit_cast(uint32_t, f);
  u += 0x7FFFu + ((u >> 16) & 1u);
  return (u16)(u >> 16);
}

static __device__ __forceinline__ float exp2_fast(float x){
  float r;
  asm("v_exp_f32 %0, %1" : "=v"(r) : "v"(x));
  return r;
}

static __device__ __forceinline__ uint32_t cvt_pk_bf16(float lo, float hi){
  uint32_t r;
  asm("v_cvt_pk_bf16_f32 %0, %1, %2" : "=v"(r) : "v"(lo), "v"(hi));
  return r;
}

static __device__ __forceinline__ void gload16(const u16* g, u16* l){
  __builtin_amdgcn_global_load_lds(
      (__attribute__((address_space(1))) uint32_t*)(uintptr_t)g,
      (__attribute__((address_space(3))) uint32_t*)l,
      16, 0, 0);
}

__global__ __launch_bounds__(256)
void cvt_bf16(const float* __restrict__ in, u16* __restrict__ out, int n){
  const int i = (blockIdx.x * 256 + threadIdx.x) * 8;
  if (i >= n) return;
  float4 a = *(const float4*)(in + i);
  float4 b = *(const float4*)(in + i + 4);
  union { u16 h[8]; uint4 v; } t;
  t.h[0]=f2bf(a.x); t.h[1]=f2bf(a.y); t.h[2]=f2bf(a.z); t.h[3]=f2bf(a.w);
  t.h[4]=f2bf(b.x); t.h[5]=f2bf(b.y); t.h[6]=f2bf(b.z); t.h[7]=f2bf(b.w);
  *(uint4*)(out + i) = t.v;
}

// C[M,N] = A[M,K] @ B[N,K]^T (m97 structure, unchanged).
template <bool F32OUT>
__global__ __launch_bounds__(256)
void gemm_bt(const u16* __restrict__ A, const u16* __restrict__ B,
             void* __restrict__ Cv, int M, int N, int K){
  constexpr int BK = 32;
  __shared__ __attribute__((aligned(16))) u16 As[128*BK];
  __shared__ __attribute__((aligned(16))) u16 Bs[128*BK];
  const int tid  = threadIdx.x;
  const int wave = tid >> 6, lane = tid & 63;
  const int quad = lane >> 4, l16 = lane & 15;
  const int wrow = wave >> 1, wcol = wave & 1;
  const int m0 = blockIdx.y * 128, n0 = blockIdx.x * 128;
  const int srow = lane >> 2, scol = (lane & 3) * 8;

  const f32x4 zero = {0.f, 0.f, 0.f, 0.f};
  f32x4 acc[4][4];
#pragma unroll
  for (int i = 0; i < 4; i++)
#pragma unroll
    for (int j = 0; j < 4; j++) acc[i][j] = zero;

  for (int k0 = 0; k0 < K; k0 += BK){
#pragma unroll
    for (int t = 0; t < 2; t++){
      const int chunk = wave + t*4;
      gload16(A + (size_t)(m0 + chunk*16 + srow)*K + k0 + scol, As + chunk*16*BK);
      gload16(B + (size_t)(n0 + chunk*16 + srow)*K + k0 + scol, Bs + chunk*16*BK);
    }
    __syncthreads();
    bf16x8 af[4], bfr[4];
#pragma unroll
    for (int mi = 0; mi < 4; mi++)
      af[mi] = *(const bf16x8*)(As + (wrow*64 + mi*16 + l16)*BK + quad*8);
#pragma unroll
    for (int ni = 0; ni < 4; ni++)
      bfr[ni] = *(const bf16x8*)(Bs + (wcol*64 + ni*16 + l16)*BK + quad*8);
#pragma unroll
    for (int mi = 0; mi < 4; mi++)
#pragma unroll
      for (int ni = 0; ni < 4; ni++)
        acc[mi][ni] = __builtin_amdgcn_mfma_f32_16x16x32_bf16(af[mi], bfr[ni], acc[mi][ni], 0, 0, 0);
    __syncthreads();
  }
#pragma unroll
  for (int mi = 0; mi < 4; mi++)
#pragma unroll
    for (int ni = 0; ni < 4; ni++){
      const int col = n0 + wcol*64 + ni*16 + l16;
#pragma unroll
      for (int r = 0; r < 4; r++){
        const int row = m0 + wrow*64 + mi*16 + quad*4 + r;
        if constexpr (F32OUT)
          ((float*)Cv)[(size_t)row*N + col] = acc[mi][ni][r];
        else
          ((u16*)Cv)[(size_t)row*N + col] = f2bf(acc[mi][ni][r]);
      }
    }
}

// V^T pre-transpose with PV k-order permutation baked into the column order:
// within each 64-key tile, column (32*ss + 8*q + 4*ni' + r) holds key
// ((2*ss+ni')*16 + q*4 + r). attn then reads V fragments at natural offsets
// while each lane's own P values form its A-fragment.
__global__ __launch_bounds__(256)
void vtrans(const u16* __restrict__ QKV, u16* __restrict__ VT){
  __shared__ u16 Ls[64*72];
  const int tid = threadIdx.x;
  const int st = blockIdx.x, hk = blockIdx.y, b = blockIdx.z;
  const size_t rb = (size_t)b * SEQ;
#pragma unroll
  for (int t = 0; t < 2; t++){
    const int task = t*256 + tid;
    const int r = task >> 3, c = task & 7;
    *(uint4*)(Ls + r*72 + c*8) =
        *(const uint4*)(QKV + (rb + st*64 + r)*QKV_DIM + 2560 + hk*HEAD_DIM + c*8);
  }
  __syncthreads();
  u16* vt_g = VT + ((size_t)(b*8 + hk) * 64) * SEQ;
#pragma unroll
  for (int t = 0; t < 2; t++){
    const int task = t*256 + tid;
    const int d = task >> 3, sc = task & 7;
    union { u16 h[8]; uint4 v; } tmp;
#pragma unroll
    for (int e = 0; e < 8; e++){
      const int key = ((2*(sc>>2) + (e>>2))<<4) + ((sc&3)<<2) + (e&3);
      tmp.h[e] = Ls[key*72 + d];
    }
    *(uint4*)(vt_g + (size_t)d*SEQ + st*64 + sc*8) = tmp.v;
  }
}

// attn: swapped QK^T, in-register P, log2 softmax + defer-max, cvt_pk, LPT.
__global__ __launch_bounds__(256)
void attn(const u16* __restrict__ Q, const u16* __restrict__ Kp,
          const u16* __restrict__ VT, u16* __restrict__ O, int qs, int ks){
  constexpr int KP = 72;
  __shared__ __attribute__((aligned(16))) u16 Ks[64*KP];
  __shared__ __attribute__((aligned(16))) u16 Vt[64*KP];
  const int tid = threadIdx.x;
  const int wave = tid >> 6, lane = tid & 63, quad = lane >> 4, l16 = lane & 15;
  const int qt = (SEQ/64 - 1) - blockIdx.x;   // LPT: longest blocks first
  const int h = blockIdx.y, b = blockIdx.z;
  const int hk = h >> 2;
  const size_t rb = (size_t)b * SEQ;
  const u16* vt_g = VT + ((size_t)(b*8 + hk) * 64) * SEQ;

  const int sr = tid >> 2, sc = tid & 3;
  const int qrow = wave*16 + l16;   // this lane's q-row (swapped layout)
  const float SCL = 0.125f * 1.44269504f;   // scale * log2(e): log2-domain

  bf16x8 qf[2];
  {
    const u16* qp = Q + (rb + qt*64 + wave*16 + l16)*qs + h*HEAD_DIM;
    qf[0] = *(const bf16x8*)(qp + quad*8);
    qf[1] = *(const bf16x8*)(qp + 32 + quad*8);
  }
  const f32x4 zero = {0.f, 0.f, 0.f, 0.f};
  f32x4 oacc[4];
#pragma unroll
  for (int i = 0; i < 4; i++) oacc[i] = zero;
  float m_i = -INFINITY;   // running max in log2 units
  float l_i = 0.f;

  // prologue: prefetch tile j=0 into registers
  uint4 kreg0, kreg1, vreg0, vreg1;
  {
    const u16* kg = Kp + (rb + sr)*ks + hk*HEAD_DIM;
    kreg0 = *(const uint4*)(kg + sc*8);
    kreg1 = *(const uint4*)(kg + (sc+4)*8);
    const u16* vg = vt_g + (size_t)sr*SEQ;
    vreg0 = *(const uint4*)(vg + sc*8);
    vreg1 = *(const uint4*)(vg + (sc+4)*8);
  }

  for (int j = 0; j <= qt; ++j){
    *(uint4*)(Ks + sr*KP + sc*8)     = kreg0;
    *(uint4*)(Ks + sr*KP + (sc+4)*8) = kreg1;
    *(uint4*)(Vt + sr*KP + sc*8)     = vreg0;
    *(uint4*)(Vt + sr*KP + (sc+4)*8) = vreg1;
    __syncthreads();
    if (j < qt){
      const u16* kg = Kp + (rb + (j+1)*64 + sr)*ks + hk*HEAD_DIM;
      kreg0 = *(const uint4*)(kg + sc*8);
      kreg1 = *(const uint4*)(kg + (sc+4)*8);
      const u16* vg = vt_g + (size_t)sr*SEQ + (j+1)*64;
      vreg0 = *(const uint4*)(vg + sc*8);
      vreg1 = *(const uint4*)(vg + (sc+4)*8);
    }

    // QK^T swapped: st[ni][r] = S2[key = j*64 + ni*16 + quad*4 + r][qrow l16]
    f32x4 st[4];
#pragma unroll
    for (int ni = 0; ni < 4; ni++){
      f32x4 s = zero;
#pragma unroll
      for (int ss = 0; ss < 2; ss++){
        bf16x8 kf = *(const bf16x8*)(Ks + (ni*16 + l16)*KP + ss*32 + quad*8);
        s = __builtin_amdgcn_mfma_f32_16x16x32_bf16(kf, qf[ss], s, 0, 0, 0);
      }
#pragma unroll
      for (int r = 0; r < 4; r++) st[ni][r] = s[r] * SCL;
    }
    if (j == qt){
#pragma unroll
      for (int ni = 0; ni < 4; ni++)
#pragma unroll
        for (int r = 0; r < 4; r++)
          if (ni*16 + quad*4 + r > qrow) st[ni][r] = -INFINITY;
    }

    // row max (16 in-lane + 2 shfl across quads)
    float mx = fmaxf(fmaxf(fmaxf(st[0][0], st[0][1]), fmaxf(st[0][2], st[0][3])),
                     fmaxf(fmaxf(st[1][0], st[1][1]), fmaxf(st[1][2], st[1][3])));
    mx = fmaxf(mx, fmaxf(fmaxf(fmaxf(st[2][0], st[2][1]), fmaxf(st[2][2], st[2][3])),
                         fmaxf(fmaxf(st[3][0], st[3][1]), fmaxf(st[3][2], st[3][3]))));
    mx = fmaxf(mx, __shfl_xor(mx, 16));
    mx = fmaxf(mx, __shfl_xor(mx, 32));

    if (__all(mx <= m_i + 10.f)){
      // defer-max: keep m_i, alpha == 1, skip rescale entirely (p <= 2^10)
      float ps = 0.f;
#pragma unroll
      for (int ni = 0; ni < 4; ni++)
#pragma unroll
        for (int r = 0; r < 4; r++){
          const float p = exp2_fast(st[ni][r] - m_i);
          st[ni][r] = p;
          ps += p;
        }
      ps += __shfl_xor(ps, 16);
      ps += __shfl_xor(ps, 32);
      l_i += ps;
    } else {
      const float mn = fmaxf(m_i, mx);
      const float alpha = exp2_fast(m_i - mn);
      float ps = 0.f;
#pragma unroll
      for (int ni = 0; ni < 4; ni++)
#pragma unroll
        for (int r = 0; r < 4; r++){
          const float p = exp2_fast(st[ni][r] - mn);
          st[ni][r] = p;
          ps += p;
        }
      ps += __shfl_xor(ps, 16);
      ps += __shfl_xor(ps, 32);
      l_i = l_i*alpha + ps;
      m_i = mn;
      float ar[4];
#pragma unroll
      for (int r = 0; r < 4; r++) ar[r] = __shfl(alpha, quad*4 + r);
#pragma unroll
      for (int ci = 0; ci < 4; ci++)
#pragma unroll
        for (int r = 0; r < 4; r++) oacc[ci][r] *= ar[r];
    }

    // P stays in registers: packed bf16 via v_cvt_pk_bf16_f32 (T12 primitive).
    // pfr[ss] element [n2*4+r] = P[key (2ss+n2)*16 + quad*4 + r]
    bf16x8 pfr[2];
#pragma unroll
    for (int ss = 0; ss < 2; ss++){
      union { uint32_t w[4]; bf16x8 v; } pk;
      pk.w[0] = cvt_pk_bf16(st[2*ss][0],   st[2*ss][1]);
      pk.w[1] = cvt_pk_bf16(st[2*ss][2],   st[2*ss][3]);
      pk.w[2] = cvt_pk_bf16(st[2*ss+1][0], st[2*ss+1][1]);
      pk.w[3] = cvt_pk_bf16(st[2*ss+1][2], st[2*ss+1][3]);
      pfr[ss] = pk.v;
    }

#pragma unroll
    for (int ss = 0; ss < 2; ss++)
#pragma unroll
      for (int ci = 0; ci < 4; ci++){
        bf16x8 vf = *(const bf16x8*)(Vt + (ci*16 + l16)*KP + ss*32 + quad*8);
        oacc[ci] = __builtin_amdgcn_mfma_f32_16x16x32_bf16(pfr[ss], vf, oacc[ci], 0, 0, 0);
      }
    __syncthreads();
  }

  // final: l_i lives in lane-space (row=l16); broadcast to row-space
  float lf[4];
#pragma unroll
  for (int r = 0; r < 4; r++) lf[r] = __shfl(l_i, quad*4 + r);
#pragma unroll
  for (int ci = 0; ci < 4; ci++)
#pragma unroll
    for (int r = 0; r < 4; r++){
      const size_t row = rb + qt*64 + wave*16 + quad*4 + r;
      O[row*D_MODEL + h*HEAD_DIM + ci*16 + l16] = f2bf(oacc[ci][r] / lf[r]);
    }
}

extern "C" void kernel_launch(void* const* d_in, const int* in_sizes, int n_in,
                              void* d_out, int out_size, void* d_ws, size_t ws_size,
                              hipStream_t stream){
  const float* x  = (const float*)d_in[0];
  const float* Wq = (const float*)d_in[1];
  const float* Wk = (const float*)d_in[2];
  const float* Wv = (const float*)d_in[3];
  const float* Wo = (const float*)d_in[4];
  float* out = (float*)d_out;

  u16* xb   = (u16*)d_ws;                    // x / later attn-out  [4096,2048]
  u16* Wb   = xb + (size_t)MTOT*D_MODEL;     // fused weights [3072,2048]
  u16* VTb  = Wb + (size_t)QKV_DIM*D_MODEL;  // V^T [16*64, 2048] (own slot)
  u16* QKVb = (u16*)d_out;                   // QKV scratch [4096,3072] bf16

  const int nx  = MTOT*D_MODEL;
  const int nwq = D_MODEL*D_MODEL;
  const int nwk = 512*D_MODEL;

  cvt_bf16<<<nx/2048, 256, 0, stream>>>(x, xb, nx);
  cvt_bf16<<<nwq/2048, 256, 0, stream>>>(Wq, Wb, nwq);
  cvt_bf16<<<nwk/2048, 256, 0, stream>>>(Wk, Wb + (size_t)D_MODEL*D_MODEL, nwk);
  cvt_bf16<<<nwk/2048, 256, 0, stream>>>(Wv, Wb + (size_t)2560*D_MODEL, nwk);
  gemm_bt<false><<<dim3(QKV_DIM/128, MTOT/128), 256, 0, stream>>>(xb, Wb, QKVb, MTOT, QKV_DIM, D_MODEL);
  vtrans<<<dim3(SEQ/64, 8, 2), 256, 0, stream>>>(QKVb, VTb);
  attn<<<dim3(SEQ/64, NUM_HEADS, 2), 256, 0, stream>>>(
      QKVb, QKVb + D_MODEL, VTb, xb, QKV_DIM, QKV_DIM);
  cvt_bf16<<<nwq/2048, 256, 0, stream>>>(Wo, Wb, nwq);
  gemm_bt<true><<<dim3(D_MODEL/128, MTOT/128), 256, 0, stream>>>(xb, Wb, (void*)out, MTOT, D_MODEL, D_MODEL);
}

// Round 6
// 347.222 us; speedup vs baseline: 1.2224x; 1.0961x over previous
//
#include <hip/hip_runtime.h>
#include <stdint.h>

// R12: base = R11 verbatim except ONE line in attn: the qt work assignment.
// Diagnosis: with x-fastest grid and XCD/CU round-robin dispatch, every
// block resident on a CU had the SAME qt (work depends only on x%32) ->
// per-CU work ranged 8..256 iterations; dispatch was tail-bound (~15%
// occupancy, all pipes <32%). Fix: complementary pairing across the batch
// dim: g=(x+y)&31, qt = z ? 31-g : g. CUs receiving matched b=0/b=1
// partners get exactly 33 iters per pair -> 132 iters/CU, exact balance.
// Still a bijection over (qt,h,b); no dataflow change.

typedef unsigned short u16;
typedef short bf16x8 __attribute__((ext_vector_type(8)));
typedef float f32x4 __attribute__((ext_vector_type(4)));

#define D_MODEL 2048
#define QKV_DIM 3072
#define NUM_HEADS 32
#define HEAD_DIM 64
#define SEQ 2048
#define MTOT 4096

static __device__ __forceinline__ u16 f2bf(float f){
  uint32_t u = __builtin_bit_cast(uint32_t, f);
  u += 0x7FFFu + ((u >> 16) & 1u);
  return (u16)(u >> 16);
}

static __device__ __forceinline__ float exp2_fast(float x){
  float r;
  asm("v_exp_f32 %0, %1" : "=v"(r) : "v"(x));
  return r;
}

static __device__ __forceinline__ uint32_t cvt_pk_bf16(float lo, float hi){
  uint32_t r;
  asm("v_cvt_pk_bf16_f32 %0, %1, %2" : "=v"(r) : "v"(lo), "v"(hi));
  return r;
}

static __device__ __forceinline__ void gload16(const u16* g, u16* l){
  __builtin_amdgcn_global_load_lds(
      (__attribute__((address_space(1))) uint32_t*)(uintptr_t)g,
      (__attribute__((address_space(3))) uint32_t*)l,
      16, 0, 0);
}

__global__ __launch_bounds__(256)
void cvt_bf16(const float* __restrict__ in, u16* __restrict__ out, int n){
  const int i = (blockIdx.x * 256 + threadIdx.x) * 8;
  if (i >= n) return;
  float4 a = *(const float4*)(in + i);
  float4 b = *(const float4*)(in + i + 4);
  union { u16 h[8]; uint4 v; } t;
  t.h[0]=f2bf(a.x); t.h[1]=f2bf(a.y); t.h[2]=f2bf(a.z); t.h[3]=f2bf(a.w);
  t.h[4]=f2bf(b.x); t.h[5]=f2bf(b.y); t.h[6]=f2bf(b.z); t.h[7]=f2bf(b.w);
  *(uint4*)(out + i) = t.v;
}

// C[M,N] = A[M,K] @ B[N,K]^T (m97 structure, unchanged).
template <bool F32OUT>
__global__ __launch_bounds__(256)
void gemm_bt(const u16* __restrict__ A, const u16* __restrict__ B,
             void* __restrict__ Cv, int M, int N, int K){
  constexpr int BK = 32;
  __shared__ __attribute__((aligned(16))) u16 As[128*BK];
  __shared__ __attribute__((aligned(16))) u16 Bs[128*BK];
  const int tid  = threadIdx.x;
  const int wave = tid >> 6, lane = tid & 63;
  const int quad = lane >> 4, l16 = lane & 15;
  const int wrow = wave >> 1, wcol = wave & 1;
  const int m0 = blockIdx.y * 128, n0 = blockIdx.x * 128;
  const int srow = lane >> 2, scol = (lane & 3) * 8;

  const f32x4 zero = {0.f, 0.f, 0.f, 0.f};
  f32x4 acc[4][4];
#pragma unroll
  for (int i = 0; i < 4; i++)
#pragma unroll
    for (int j = 0; j < 4; j++) acc[i][j] = zero;

  for (int k0 = 0; k0 < K; k0 += BK){
#pragma unroll
    for (int t = 0; t < 2; t++){
      const int chunk = wave + t*4;
      gload16(A + (size_t)(m0 + chunk*16 + srow)*K + k0 + scol, As + chunk*16*BK);
      gload16(B + (size_t)(n0 + chunk*16 + srow)*K + k0 + scol, Bs + chunk*16*BK);
    }
    __syncthreads();
    bf16x8 af[4], bfr[4];
#pragma unroll
    for (int mi = 0; mi < 4; mi++)
      af[mi] = *(const bf16x8*)(As + (wrow*64 + mi*16 + l16)*BK + quad*8);
#pragma unroll
    for (int ni = 0; ni < 4; ni++)
      bfr[ni] = *(const bf16x8*)(Bs + (wcol*64 + ni*16 + l16)*BK + quad*8);
#pragma unroll
    for (int mi = 0; mi < 4; mi++)
#pragma unroll
      for (int ni = 0; ni < 4; ni++)
        acc[mi][ni] = __builtin_amdgcn_mfma_f32_16x16x32_bf16(af[mi], bfr[ni], acc[mi][ni], 0, 0, 0);
    __syncthreads();
  }
#pragma unroll
  for (int mi = 0; mi < 4; mi++)
#pragma unroll
    for (int ni = 0; ni < 4; ni++){
      const int col = n0 + wcol*64 + ni*16 + l16;
#pragma unroll
      for (int r = 0; r < 4; r++){
        const int row = m0 + wrow*64 + mi*16 + quad*4 + r;
        if constexpr (F32OUT)
          ((float*)Cv)[(size_t)row*N + col] = acc[mi][ni][r];
        else
          ((u16*)Cv)[(size_t)row*N + col] = f2bf(acc[mi][ni][r]);
      }
    }
}

// V^T pre-transpose with PV k-order permutation baked into the column order:
// within each 64-key tile, column (32*ss + 8*q + 4*ni' + r) holds key
// ((2*ss+ni')*16 + q*4 + r). attn then reads V fragments at natural offsets
// while each lane's own P values form its A-fragment.
__global__ __launch_bounds__(256)
void vtrans(const u16* __restrict__ QKV, u16* __restrict__ VT){
  __shared__ u16 Ls[64*72];
  const int tid = threadIdx.x;
  const int st = blockIdx.x, hk = blockIdx.y, b = blockIdx.z;
  const size_t rb = (size_t)b * SEQ;
#pragma unroll
  for (int t = 0; t < 2; t++){
    const int task = t*256 + tid;
    const int r = task >> 3, c = task & 7;
    *(uint4*)(Ls + r*72 + c*8) =
        *(const uint4*)(QKV + (rb + st*64 + r)*QKV_DIM + 2560 + hk*HEAD_DIM + c*8);
  }
  __syncthreads();
  u16* vt_g = VT + ((size_t)(b*8 + hk) * 64) * SEQ;
#pragma unroll
  for (int t = 0; t < 2; t++){
    const int task = t*256 + tid;
    const int d = task >> 3, sc = task & 7;
    union { u16 h[8]; uint4 v; } tmp;
#pragma unroll
    for (int e = 0; e < 8; e++){
      const int key = ((2*(sc>>2) + (e>>2))<<4) + ((sc&3)<<2) + (e&3);
      tmp.h[e] = Ls[key*72 + d];
    }
    *(uint4*)(vt_g + (size_t)d*SEQ + st*64 + sc*8) = tmp.v;
  }
}

// attn: swapped QK^T, in-register P, log2 softmax + defer-max, cvt_pk,
// complement-balanced work assignment.
__global__ __launch_bounds__(256)
void attn(const u16* __restrict__ Q, const u16* __restrict__ Kp,
          const u16* __restrict__ VT, u16* __restrict__ O, int qs, int ks){
  constexpr int KP = 72;
  __shared__ __attribute__((aligned(16))) u16 Ks[64*KP];
  __shared__ __attribute__((aligned(16))) u16 Vt[64*KP];
  const int tid = threadIdx.x;
  const int wave = tid >> 6, lane = tid & 63, quad = lane >> 4, l16 = lane & 15;
  // complement-balanced qt: CUs receiving matched b=0/b=1 partners do 33
  // iters per pair regardless of x -> exact per-CU balance under XCD/CU
  // round-robin dispatch (work depends only on qt).
  const int g_ = (blockIdx.x + blockIdx.y) & 31;
  const int qt = blockIdx.z ? (31 - g_) : g_;
  const int h = blockIdx.y, b = blockIdx.z;
  const int hk = h >> 2;
  const size_t rb = (size_t)b * SEQ;
  const u16* vt_g = VT + ((size_t)(b*8 + hk) * 64) * SEQ;

  const int sr = tid >> 2, sc = tid & 3;
  const int qrow = wave*16 + l16;   // this lane's q-row (swapped layout)
  const float SCL = 0.125f * 1.44269504f;   // scale * log2(e): log2-domain

  bf16x8 qf[2];
  {
    const u16* qp = Q + (rb + qt*64 + wave*16 + l16)*qs + h*HEAD_DIM;
    qf[0] = *(const bf16x8*)(qp + quad*8);
    qf[1] = *(const bf16x8*)(qp + 32 + quad*8);
  }
  const f32x4 zero = {0.f, 0.f, 0.f, 0.f};
  f32x4 oacc[4];
#pragma unroll
  for (int i = 0; i < 4; i++) oacc[i] = zero;
  float m_i = -INFINITY;   // running max in log2 units
  float l_i = 0.f;

  // prologue: prefetch tile j=0 into registers
  uint4 kreg0, kreg1, vreg0, vreg1;
  {
    const u16* kg = Kp + (rb + sr)*ks + hk*HEAD_DIM;
    kreg0 = *(const uint4*)(kg + sc*8);
    kreg1 = *(const uint4*)(kg + (sc+4)*8);
    const u16* vg = vt_g + (size_t)sr*SEQ;
    vreg0 = *(const uint4*)(vg + sc*8);
    vreg1 = *(const uint4*)(vg + (sc+4)*8);
  }

  for (int j = 0; j <= qt; ++j){
    *(uint4*)(Ks + sr*KP + sc*8)     = kreg0;
    *(uint4*)(Ks + sr*KP + (sc+4)*8) = kreg1;
    *(uint4*)(Vt + sr*KP + sc*8)     = vreg0;
    *(uint4*)(Vt + sr*KP + (sc+4)*8) = vreg1;
    __syncthreads();
    if (j < qt){
      const u16* kg = Kp + (rb + (j+1)*64 + sr)*ks + hk*HEAD_DIM;
      kreg0 = *(const uint4*)(kg + sc*8);
      kreg1 = *(const uint4*)(kg + (sc+4)*8);
      const u16* vg = vt_g + (size_t)sr*SEQ + (j+1)*64;
      vreg0 = *(const uint4*)(vg + sc*8);
      vreg1 = *(const uint4*)(vg + (sc+4)*8);
    }

    // QK^T swapped: st[ni][r] = S2[key = j*64 + ni*16 + quad*4 + r][qrow l16]
    f32x4 st[4];
#pragma unroll
    for (int ni = 0; ni < 4; ni++){
      f32x4 s = zero;
#pragma unroll
      for (int ss = 0; ss < 2; ss++){
        bf16x8 kf = *(const bf16x8*)(Ks + (ni*16 + l16)*KP + ss*32 + quad*8);
        s = __builtin_amdgcn_mfma_f32_16x16x32_bf16(kf, qf[ss], s, 0, 0, 0);
      }
#pragma unroll
      for (int r = 0; r < 4; r++) st[ni][r] = s[r] * SCL;
    }
    if (j == qt){
#pragma unroll
      for (int ni = 0; ni < 4; ni++)
#pragma unroll
        for (int r = 0; r < 4; r++)
          if (ni*16 + quad*4 + r > qrow) st[ni][r] = -INFINITY;
    }

    // row max (16 in-lane + 2 shfl across quads)
    float mx = fmaxf(fmaxf(fmaxf(st[0][0], st[0][1]), fmaxf(st[0][2], st[0][3])),
                     fmaxf(fmaxf(st[1][0], st[1][1]), fmaxf(st[1][2], st[1][3])));
    mx = fmaxf(mx, fmaxf(fmaxf(fmaxf(st[2][0], st[2][1]), fmaxf(st[2][2], st[2][3])),
                         fmaxf(fmaxf(st[3][0], st[3][1]), fmaxf(st[3][2], st[3][3]))));
    mx = fmaxf(mx, __shfl_xor(mx, 16));
    mx = fmaxf(mx, __shfl_xor(mx, 32));

    if (__all(mx <= m_i + 10.f)){
      // defer-max: keep m_i, alpha == 1, skip rescale entirely (p <= 2^10)
      float ps = 0.f;
#pragma unroll
      for (int ni = 0; ni < 4; ni++)
#pragma unroll
        for (int r = 0; r < 4; r++){
          const float p = exp2_fast(st[ni][r] - m_i);
          st[ni][r] = p;
          ps += p;
        }
      ps += __shfl_xor(ps, 16);
      ps += __shfl_xor(ps, 32);
      l_i += ps;
    } else {
      const float mn = fmaxf(m_i, mx);
      const float alpha = exp2_fast(m_i - mn);
      float ps = 0.f;
#pragma unroll
      for (int ni = 0; ni < 4; ni++)
#pragma unroll
        for (int r = 0; r < 4; r++){
          const float p = exp2_fast(st[ni][r] - mn);
          st[ni][r] = p;
          ps += p;
        }
      ps += __shfl_xor(ps, 16);
      ps += __shfl_xor(ps, 32);
      l_i = l_i*alpha + ps;
      m_i = mn;
      float ar[4];
#pragma unroll
      for (int r = 0; r < 4; r++) ar[r] = __shfl(alpha, quad*4 + r);
#pragma unroll
      for (int ci = 0; ci < 4; ci++)
#pragma unroll
        for (int r = 0; r < 4; r++) oacc[ci][r] *= ar[r];
    }

    // P stays in registers: packed bf16 via v_cvt_pk_bf16_f32 (T12 primitive).
    // pfr[ss] element [n2*4+r] = P[key (2ss+n2)*16 + quad*4 + r]
    bf16x8 pfr[2];
#pragma unroll
    for (int ss = 0; ss < 2; ss++){
      union { uint32_t w[4]; bf16x8 v; } pk;
      pk.w[0] = cvt_pk_bf16(st[2*ss][0],   st[2*ss][1]);
      pk.w[1] = cvt_pk_bf16(st[2*ss][2],   st[2*ss][3]);
      pk.w[2] = cvt_pk_bf16(st[2*ss+1][0], st[2*ss+1][1]);
      pk.w[3] = cvt_pk_bf16(st[2*ss+1][2], st[2*ss+1][3]);
      pfr[ss] = pk.v;
    }

#pragma unroll
    for (int ss = 0; ss < 2; ss++)
#pragma unroll
      for (int ci = 0; ci < 4; ci++){
        bf16x8 vf = *(const bf16x8*)(Vt + (ci*16 + l16)*KP + ss*32 + quad*8);
        oacc[ci] = __builtin_amdgcn_mfma_f32_16x16x32_bf16(pfr[ss], vf, oacc[ci], 0, 0, 0);
      }
    __syncthreads();
  }

  // final: l_i lives in lane-space (row=l16); broadcast to row-space
  float lf[4];
#pragma unroll
  for (int r = 0; r < 4; r++) lf[r] = __shfl(l_i, quad*4 + r);
#pragma unroll
  for (int ci = 0; ci < 4; ci++)
#pragma unroll
    for (int r = 0; r < 4; r++){
      const size_t row = rb + qt*64 + wave*16 + quad*4 + r;
      O[row*D_MODEL + h*HEAD_DIM + ci*16 + l16] = f2bf(oacc[ci][r] / lf[r]);
    }
}

extern "C" void kernel_launch(void* const* d_in, const int* in_sizes, int n_in,
                              void* d_out, int out_size, void* d_ws, size_t ws_size,
                              hipStream_t stream){
  const float* x  = (const float*)d_in[0];
  const float* Wq = (const float*)d_in[1];
  const float* Wk = (const float*)d_in[2];
  const float* Wv = (const float*)d_in[3];
  const float* Wo = (const float*)d_in[4];
  float* out = (float*)d_out;

  u16* xb   = (u16*)d_ws;                    // x / later attn-out  [4096,2048]
  u16* Wb   = xb + (size_t)MTOT*D_MODEL;     // fused weights [3072,2048]
  u16* VTb  = Wb + (size_t)QKV_DIM*D_MODEL;  // V^T [16*64, 2048] (own slot)
  u16* QKVb = (u16*)d_out;                   // QKV scratch [4096,3072] bf16

  const int nx  = MTOT*D_MODEL;
  const int nwq = D_MODEL*D_MODEL;
  const int nwk = 512*D_MODEL;

  cvt_bf16<<<nx/2048, 256, 0, stream>>>(x, xb, nx);
  cvt_bf16<<<nwq/2048, 256, 0, stream>>>(Wq, Wb, nwq);
  cvt_bf16<<<nwk/2048, 256, 0, stream>>>(Wk, Wb + (size_t)D_MODEL*D_MODEL, nwk);
  cvt_bf16<<<nwk/2048, 256, 0, stream>>>(Wv, Wb + (size_t)2560*D_MODEL, nwk);
  gemm_bt<false><<<dim3(QKV_DIM/128, MTOT/128), 256, 0, stream>>>(xb, Wb, QKVb, MTOT, QKV_DIM, D_MODEL);
  vtrans<<<dim3(SEQ/64, 8, 2), 256, 0, stream>>>(QKVb, VTb);
  attn<<<dim3(SEQ/64, NUM_HEADS, 2), 256, 0, stream>>>(
      QKVb, QKVb + D_MODEL, VTb, xb, QKV_DIM, QKV_DIM);
  cvt_bf16<<<nwq/2048, 256, 0, stream>>>(Wo, Wb, nwq);
  gemm_bt<true><<<dim3(D_MODEL/128, MTOT/128), 256, 0, stream>>>(xb, Wb, (void*)out, MTOT, D_MODEL, D_MODEL);
}